// Round 8
// baseline (13251.962 us; speedup 1.0000x reference)
//
#include <hip/hip_runtime.h>
#include <hip/hip_bf16.h>
#include <math.h>

// Problem constants
#define B_    4
#define T_    1024
#define E_    1024
#define H_    8
#define DH_   128
#define MEM_  1024
#define CMEM_ 256
#define KVLEN 2304              // CMEM + MEM + T
#define SCALE 0.08838834764831845f   // 1/sqrt(128)

// ---------------------------------------------------------------------------
// Generic tiled f32 GEMM: C[M,N] = A[M,K] @ B[N,K]^T (+bias)
// AMODE 0: plain A pointer (row-major M x K)
// AMODE 1: A row r gathers from concat(cmem, mem, x) along kv axis
// AMODE 2: A is im2col of mem for the stride-4 conv: A[bs, c*4+r] = mem[b,4s+r,c]
// ---------------------------------------------------------------------------
template<int AMODE>
__global__ __launch_bounds__(256)
void gemm_kernel(const float* __restrict__ A, const float* __restrict__ Bm,
                 const float* __restrict__ bias, float* __restrict__ C,
                 int M, int N, int K,
                 const float* __restrict__ aux0, const float* __restrict__ aux1,
                 const float* __restrict__ aux2)
{
    __shared__ float As[16][65];   // [k][m], +1 pad
    __shared__ float Bs[16][65];   // [k][n]
    const int bm = blockIdx.y * 64, bn = blockIdx.x * 64;
    const int tid = threadIdx.x;
    const int tx = tid & 15, ty = tid >> 4;
    float acc[4][4] = {};

    for (int k0 = 0; k0 < K; k0 += 16) {
#pragma unroll
        for (int l = 0; l < 4; ++l) {
            int e = tid + l * 256;
            int m = e >> 4, kk = e & 15;
            int row = bm + m, k = k0 + kk;
            float v;
            if (AMODE == 0) {
                v = A[(size_t)row * K + k];
            } else if (AMODE == 1) {
                int b = row / KVLEN, t = row % KVLEN;
                const float* src;
                if (t < CMEM_)             src = aux0 + ((size_t)(b * CMEM_ + t)) * E_;
                else if (t < CMEM_ + MEM_) src = aux1 + ((size_t)(b * MEM_ + (t - CMEM_))) * E_;
                else                       src = aux2 + ((size_t)(b * T_ + (t - CMEM_ - MEM_))) * E_;
                v = src[k];
            } else {
                int b = row >> 8, s = row & 255;
                v = aux0[((size_t)(b * MEM_) + (4 * s + (k & 3))) * E_ + (k >> 2)];
            }
            As[kk][m] = v;
        }
#pragma unroll
        for (int l = 0; l < 4; ++l) {
            int e = tid + l * 256;
            int n = e >> 4, kk = e & 15;
            Bs[kk][n] = Bm[(size_t)(bn + n) * K + k0 + kk];
        }
        __syncthreads();
#pragma unroll
        for (int kk = 0; kk < 16; ++kk) {
            float a[4], b[4];
#pragma unroll
            for (int i = 0; i < 4; ++i) a[i] = As[kk][ty * 4 + i];
#pragma unroll
            for (int j = 0; j < 4; ++j) b[j] = Bs[kk][tx * 4 + j];
#pragma unroll
            for (int i = 0; i < 4; ++i)
#pragma unroll
                for (int j = 0; j < 4; ++j)
                    acc[i][j] = fmaf(a[i], b[j], acc[i][j]);
        }
        __syncthreads();
    }

#pragma unroll
    for (int i = 0; i < 4; ++i) {
        int row = bm + ty * 4 + i;
#pragma unroll
        for (int j = 0; j < 4; ++j) {
            int col = bn + tx * 4 + j;
            float v = acc[i][j];
            if (bias) v += bias[col];
            C[(size_t)row * N + col] = v;
        }
    }
}

// ---------------------------------------------------------------------------
// Main attention: one block per (b,h,i) row.
// scores[j] = (q . k_j + q . pe[j + 1023 - i]) * SCALE  for j <= i + 1280
// (j + 1023 - i >= 2304 <=> j > i + 1280 : masked, matches the causal mask)
// ---------------------------------------------------------------------------
__global__ __launch_bounds__(256)
void attn_main_kernel(const float* __restrict__ q, const float* __restrict__ kv,
                      const float* __restrict__ pe, float* __restrict__ outb)
{
    __shared__ float qs[DH_];
    __shared__ float sc[KVLEN];
    __shared__ float red[256];
    const int bid = blockIdx.x;
    const int i = bid & (T_ - 1);
    const int h = (bid >> 10) & (H_ - 1);
    const int b = bid >> 13;
    const int tid = threadIdx.x;

    if (tid < DH_) qs[tid] = q[((size_t)(b * T_ + i)) * E_ + h * DH_ + tid] * SCALE;
    __syncthreads();
    const float4* q4 = (const float4*)qs;

    for (int j = tid; j < KVLEN; j += 256) {
        int p = j + (T_ - 1) - i;          // relative-position index after _shift
        if (p >= KVLEN) { sc[j] = -INFINITY; continue; }   // == causal mask
        const float4* kp = (const float4*)(kv + ((size_t)(b * KVLEN + j)) * 2048 + h * DH_);
        const float4* pp = (const float4*)(pe + ((size_t)(h * KVLEN) + p) * DH_);
        float dot = 0.f, pdot = 0.f;
#pragma unroll 8
        for (int d4 = 0; d4 < DH_ / 4; ++d4) {
            float4 qv = q4[d4], kk = kp[d4], pv = pp[d4];
            dot  = fmaf(qv.x, kk.x, fmaf(qv.y, kk.y, fmaf(qv.z, kk.z, fmaf(qv.w, kk.w, dot))));
            pdot = fmaf(qv.x, pv.x, fmaf(qv.y, pv.y, fmaf(qv.z, pv.z, fmaf(qv.w, pv.w, pdot))));
        }
        sc[j] = dot + pdot;
    }
    __syncthreads();

    // row max
    float m = -INFINITY;
    for (int j = tid; j < KVLEN; j += 256) m = fmaxf(m, sc[j]);
    red[tid] = m; __syncthreads();
    for (int s = 128; s > 0; s >>= 1) { if (tid < s) red[tid] = fmaxf(red[tid], red[tid + s]); __syncthreads(); }
    m = red[0]; __syncthreads();

    // exp + sum
    float lsum = 0.f;
    for (int j = tid; j < KVLEN; j += 256) { float e = __expf(sc[j] - m); sc[j] = e; lsum += e; }
    red[tid] = lsum; __syncthreads();
    for (int s = 128; s > 0; s >>= 1) { if (tid < s) red[tid] += red[tid + s]; __syncthreads(); }
    const float inv = 1.0f / red[0];

    // PV: 256 threads = 2 half-ranges x 128 dims
    const int d = tid & 127, hs = tid >> 7;
    float acc = 0.f;
    const float* vb = kv + 1024 + h * DH_ + d;
    for (int j = hs * 1152; j < hs * 1152 + 1152; ++j)
        acc = fmaf(sc[j], vb[((size_t)(b * KVLEN + j)) * 2048], acc);
    __syncthreads();
    red[tid] = acc; __syncthreads();
    if (tid < 128)
        outb[((size_t)(b * T_ + i)) * E_ + h * DH_ + tid] = (red[tid] + red[tid + 128]) * inv;
}

// ---------------------------------------------------------------------------
// Aux loss: per (b,h,i) row, a1 = attn(q, k[256:1280], v[256:1280]) (no mask),
// a2 = attn(q, cmem_k, cmem_v); accumulate sum((a1-a2)^2).
// ---------------------------------------------------------------------------
__global__ __launch_bounds__(256)
void attn_aux_kernel(const float* __restrict__ q, const float* __restrict__ kv,
                     const float* __restrict__ ckv, float* __restrict__ accum)
{
    __shared__ float qs[DH_];
    __shared__ float sc[MEM_];
    __shared__ float red[256];
    __shared__ float o1[DH_];
    const int bid = blockIdx.x;
    const int i = bid & (T_ - 1), h = (bid >> 10) & 7, b = bid >> 13;
    const int tid = threadIdx.x;

    if (tid < DH_) qs[tid] = q[((size_t)(b * T_ + i)) * E_ + h * DH_ + tid] * SCALE;
    __syncthreads();
    const float4* q4 = (const float4*)qs;

    // ---- a1 scores over 1024 old keys (kv rows 256..1279) ----
    for (int j = tid; j < MEM_; j += 256) {
        const float4* kp = (const float4*)(kv + ((size_t)(b * KVLEN + CMEM_ + j)) * 2048 + h * DH_);
        float dot = 0.f;
#pragma unroll 8
        for (int d4 = 0; d4 < 32; ++d4) {
            float4 qv = q4[d4], kk = kp[d4];
            dot = fmaf(qv.x, kk.x, fmaf(qv.y, kk.y, fmaf(qv.z, kk.z, fmaf(qv.w, kk.w, dot))));
        }
        sc[j] = dot;
    }
    __syncthreads();
    float m = fmaxf(fmaxf(sc[tid], sc[tid + 256]), fmaxf(sc[tid + 512], sc[tid + 768]));
    red[tid] = m; __syncthreads();
    for (int s = 128; s > 0; s >>= 1) { if (tid < s) red[tid] = fmaxf(red[tid], red[tid + s]); __syncthreads(); }
    m = red[0]; __syncthreads();
    float lsum = 0.f;
    for (int j = tid; j < MEM_; j += 256) { float e = __expf(sc[j] - m); sc[j] = e; lsum += e; }
    red[tid] = lsum; __syncthreads();
    for (int s = 128; s > 0; s >>= 1) { if (tid < s) red[tid] += red[tid + s]; __syncthreads(); }
    const float inv1 = 1.f / red[0]; __syncthreads();

    const int d = tid & 127, hs = tid >> 7;
    float acc = 0.f;
    const float* vb = kv + 1024 + h * DH_ + d;
    for (int j = hs * 512; j < hs * 512 + 512; ++j)
        acc = fmaf(sc[j], vb[((size_t)(b * KVLEN + CMEM_ + j)) * 2048], acc);
    red[tid] = acc; __syncthreads();
    if (tid < 128) o1[tid] = (red[tid] + red[tid + 128]) * inv1;
    __syncthreads();

    // ---- a2 scores over 256 compressed keys ----
    {
        const float4* kp = (const float4*)(ckv + ((size_t)(b * CMEM_ + tid)) * 2048 + h * DH_);
        float dot = 0.f;
#pragma unroll 8
        for (int d4 = 0; d4 < 32; ++d4) {
            float4 qv = q4[d4], kk = kp[d4];
            dot = fmaf(qv.x, kk.x, fmaf(qv.y, kk.y, fmaf(qv.z, kk.z, fmaf(qv.w, kk.w, dot))));
        }
        sc[tid] = dot;
    }
    __syncthreads();
    red[tid] = sc[tid]; __syncthreads();
    for (int s = 128; s > 0; s >>= 1) { if (tid < s) red[tid] = fmaxf(red[tid], red[tid + s]); __syncthreads(); }
    m = red[0]; __syncthreads();
    float e2 = __expf(sc[tid] - m); sc[tid] = e2;
    red[tid] = e2; __syncthreads();
    for (int s = 128; s > 0; s >>= 1) { if (tid < s) red[tid] += red[tid + s]; __syncthreads(); }
    const float inv2 = 1.f / red[0]; __syncthreads();

    acc = 0.f;
    const float* vb2 = ckv + 1024 + h * DH_ + d;
    for (int j = hs * 128; j < hs * 128 + 128; ++j)
        acc = fmaf(sc[j], vb2[((size_t)(b * CMEM_ + j)) * 2048], acc);
    red[tid] = acc; __syncthreads();
    float sse = 0.f;
    if (tid < 128) { float diff = (red[tid] + red[tid + 128]) * inv2 - o1[tid]; sse = diff * diff; }
    __syncthreads();
    red[tid] = sse; __syncthreads();
    for (int s = 128; s > 0; s >>= 1) { if (tid < s) red[tid] += red[tid + s]; __syncthreads(); }
    if (tid == 0) atomicAdd(accum, red[0]);
}

__global__ void zero_kernel(float* p) { if (threadIdx.x == 0) p[0] = 0.f; }

__global__ void finalize_kernel(const float* __restrict__ accum, float* __restrict__ out)
{
    out[0] = accum[0] * (1.0f / 4194304.0f);  // mean over 4*8*1024*128
}

// float4-vectorized f32 -> f32 copy
__global__ __launch_bounds__(256)
void copy_f32_kernel(const float* __restrict__ in, float* __restrict__ out, int n4)
{
    int idx = blockIdx.x * 256 + threadIdx.x;
    int stride = gridDim.x * 256;
    const float4* in4 = (const float4*)in;
    float4* out4 = (float4*)out;
    for (int i = idx; i < n4; i += stride) out4[i] = in4[i];
}

// ---------------------------------------------------------------------------
extern "C" void kernel_launch(void* const* d_in, const int* in_sizes, int n_in,
                              void* d_out, int out_size, void* d_ws, size_t ws_size,
                              hipStream_t stream)
{
    const float* x      = (const float*)d_in[0];
    const float* mem    = (const float*)d_in[1];
    const float* cmem   = (const float*)d_in[2];
    const float* pos    = (const float*)d_in[3];
    const float* w_q    = (const float*)d_in[4];
    const float* w_kv   = (const float*)d_in[5];
    const float* w_out  = (const float*)d_in[6];
    const float* b_out  = (const float*)d_in[7];
    const float* conv_w = (const float*)d_in[8];
    const float* conv_b = (const float*)d_in[9];
    float* out = (float*)d_out;          // f32 outputs: logits | new_mem | new_cmem | aux

    float* ws     = (float*)d_ws;
    float* q      = ws;                  // 4,194,304
    float* kv     = q     + 4194304;     // 18,874,368 (k | v per row of 2048)
    float* attno  = kv    + 18874368;    // 4,194,304
    float* comp   = attno + 4194304;     // 1,048,576
    float* ckv    = comp  + 1048576;     // 2,097,152
    float* accum  = ckv   + 2097152;     // 1

    dim3 blk(256);

    // q = x @ w_q^T                               (4096 x 1024 x 1024)
    gemm_kernel<0><<<dim3(1024/64, 4096/64), blk, 0, stream>>>(
        x, w_q, nullptr, q, 4096, 1024, 1024, nullptr, nullptr, nullptr);
    // kv = concat(cmem,mem,x) @ w_kv^T            (9216 x 2048 x 1024)
    gemm_kernel<1><<<dim3(2048/64, 9216/64), blk, 0, stream>>>(
        nullptr, w_kv, nullptr, kv, 9216, 2048, 1024, cmem, mem, x);
    // compressed = conv(mem) as GEMM              (1024 x 1024 x 4096)
    gemm_kernel<2><<<dim3(1024/64, 1024/64), blk, 0, stream>>>(
        nullptr, conv_w, conv_b, comp, 1024, 1024, 4096, mem, nullptr, nullptr);
    // ckv = compressed @ w_kv^T                   (1024 x 2048 x 1024)
    gemm_kernel<0><<<dim3(2048/64, 1024/64), blk, 0, stream>>>(
        comp, w_kv, nullptr, ckv, 1024, 2048, 1024, nullptr, nullptr, nullptr);
    // fused attention (qk + rel-pos + causal softmax + pv)
    attn_main_kernel<<<dim3(B_*H_*T_), blk, 0, stream>>>(q, kv, pos, attno);
    // logits = attn_out @ w_out^T + b_out  -> f32 d_out[0 : 4194304)
    gemm_kernel<0><<<dim3(1024/64, 4096/64), blk, 0, stream>>>(
        attno, w_out, b_out, out, 4096, 1024, 1024, nullptr, nullptr, nullptr);
    // new_mem = x                          -> f32 d_out[4194304 : 8388608)
    copy_f32_kernel<<<dim3(2048), blk, 0, stream>>>(x, out + 4194304, 4194304 / 4);
    // new_cmem = compressed                -> f32 d_out[8388608 : 9437184)
    copy_f32_kernel<<<dim3(1024), blk, 0, stream>>>(comp, out + 8388608, 1048576 / 4);
    // aux loss                             -> f32 d_out[9437184]
    zero_kernel<<<1, 64, 0, stream>>>(accum);
    attn_aux_kernel<<<dim3(B_*H_*T_), blk, 0, stream>>>(q, kv, ckv, accum);
    finalize_kernel<<<1, 1, 0, stream>>>(accum, out + 9437184);
}

// Round 9
// 7514.973 us; speedup vs baseline: 1.7634x; 1.7634x over previous
//
#include <hip/hip_runtime.h>
#include <hip/hip_bf16.h>
#include <math.h>

// Problem constants
#define B_    4
#define T_    1024
#define E_    1024
#define H_    8
#define DH_   128
#define MEM_  1024
#define CMEM_ 256
#define KVLEN 2304              // CMEM + MEM + T
#define SCALE 0.08838834764831845f   // 1/sqrt(128)

// ---------------------------------------------------------------------------
// Generic tiled f32 GEMM: C[M,N] = A[M,K] @ B[N,K]^T (+bias)   (unchanged)
// ---------------------------------------------------------------------------
template<int AMODE>
__global__ __launch_bounds__(256)
void gemm_kernel(const float* __restrict__ A, const float* __restrict__ Bm,
                 const float* __restrict__ bias, float* __restrict__ C,
                 int M, int N, int K,
                 const float* __restrict__ aux0, const float* __restrict__ aux1,
                 const float* __restrict__ aux2)
{
    __shared__ float As[16][65];
    __shared__ float Bs[16][65];
    const int bm = blockIdx.y * 64, bn = blockIdx.x * 64;
    const int tid = threadIdx.x;
    const int tx = tid & 15, ty = tid >> 4;
    float acc[4][4] = {};

    for (int k0 = 0; k0 < K; k0 += 16) {
#pragma unroll
        for (int l = 0; l < 4; ++l) {
            int e = tid + l * 256;
            int m = e >> 4, kk = e & 15;
            int row = bm + m, k = k0 + kk;
            float v;
            if (AMODE == 0) {
                v = A[(size_t)row * K + k];
            } else if (AMODE == 1) {
                int b = row / KVLEN, t = row % KVLEN;
                const float* src;
                if (t < CMEM_)             src = aux0 + ((size_t)(b * CMEM_ + t)) * E_;
                else if (t < CMEM_ + MEM_) src = aux1 + ((size_t)(b * MEM_ + (t - CMEM_))) * E_;
                else                       src = aux2 + ((size_t)(b * T_ + (t - CMEM_ - MEM_))) * E_;
                v = src[k];
            } else {
                int b = row >> 8, s = row & 255;
                v = aux0[((size_t)(b * MEM_) + (4 * s + (k & 3))) * E_ + (k >> 2)];
            }
            As[kk][m] = v;
        }
#pragma unroll
        for (int l = 0; l < 4; ++l) {
            int e = tid + l * 256;
            int n = e >> 4, kk = e & 15;
            Bs[kk][n] = Bm[(size_t)(bn + n) * K + k0 + kk];
        }
        __syncthreads();
#pragma unroll
        for (int kk = 0; kk < 16; ++kk) {
            float a[4], b[4];
#pragma unroll
            for (int i = 0; i < 4; ++i) a[i] = As[kk][ty * 4 + i];
#pragma unroll
            for (int j = 0; j < 4; ++j) b[j] = Bs[kk][tx * 4 + j];
#pragma unroll
            for (int i = 0; i < 4; ++i)
#pragma unroll
                for (int j = 0; j < 4; ++j)
                    acc[i][j] = fmaf(a[i], b[j], acc[i][j]);
        }
        __syncthreads();
    }

#pragma unroll
    for (int i = 0; i < 4; ++i) {
        int row = bm + ty * 4 + i;
#pragma unroll
        for (int j = 0; j < 4; ++j) {
            int col = bn + tx * 4 + j;
            float v = acc[i][j];
            if (bias) v += bias[col];
            C[(size_t)row * N + col] = v;
        }
    }
}

// ---------------------------------------------------------------------------
// Tiled main attention: one block = 32 query rows of one (b,h); K/V/pe staged
// in LDS and reused across the 32 queries (the round-8 profile showed the
// per-row kernel re-reading 115 GB; this cuts LDS-side traffic ~16-32x).
//
// scores[i][j] = (q_i.k_j + q_i.pe[j+1023-i]) * SCALE, masked for j > i+1280.
// Online softmax across key tiles of 32.
//
// Score phase: thread (qi=t>>3, g=t&7) owns q/d-slice {g*4+32c} (reg-held) and
// computes partial dots for all 32 keys; 8-lane shfl_xor all-reduce completes
// them. d-slice stride 32 floats => K reads conflict-free, pe reads BW-bound.
// PV phase: thread (w=t>>6, l=t&63) owns rows qv=l>>1, d [w*32+(l&1)*16,+16).
// ---------------------------------------------------------------------------
__global__ __launch_bounds__(256)
void attn_tiled_kernel(const float* __restrict__ q, const float* __restrict__ kv,
                       const float* __restrict__ pe, float* __restrict__ outb)
{
    __shared__ float KV[32][128];   // K tile, later V tile (16 KB)
    __shared__ float PE[64][128];   // pe rows pb..pb+62 (32 KB, row 63 unused)
    __shared__ float S[32][36];     // unnormalized probs, padded (4.6 KB)
    __shared__ float RS[32];        // per-row rescale factor
    __shared__ float LN[32];        // per-row final denominator

    const int bid = blockIdx.x;
    const int it = bid & 31, h = (bid >> 5) & 7, b = bid >> 8;
    const int i0 = it * 32;
    const int tid = threadIdx.x;
    // score-phase mapping
    const int qi = tid >> 3, g = tid & 7;
    const int i  = i0 + qi;
    // PV-phase mapping
    const int w = tid >> 6, l = tid & 63;
    const int qv = l >> 1;
    const int d4base = w * 8 + (l & 1) * 4;     // float4 index of owned d-slice

    // q slice (16 floats at g*4 + 32c), pre-scaled, in registers
    float4 qr[4];
    {
        const float4* qp = (const float4*)(q + ((size_t)(b * T_ + i)) * E_ + h * DH_);
#pragma unroll
        for (int c = 0; c < 4; ++c) {
            float4 v = qp[g + 8 * c];
            v.x *= SCALE; v.y *= SCALE; v.z *= SCALE; v.w *= SCALE;
            qr[c] = v;
        }
    }
    float o[16];
#pragma unroll
    for (int c = 0; c < 16; ++c) o[c] = 0.f;
    float mrow = -INFINITY, lrow = 0.f;

    const int NT = it + 41;          // tiles cover j <= i0+31+1280
    for (int kt = 0; kt < NT; ++kt) {
        const int j0 = kt * 32;
        const int pb = j0 - i0 + 992;            // pe row base (>=0 always)
        __syncthreads();                          // prior PV done; buffers free
        // ---- stage K (32x128) and pe band (63x128, OOB rows -> 0) ----
#pragma unroll
        for (int c = 0; c < 4; ++c) {
            int e = tid + 256 * c;               // float4 element id (1024)
            int r = e >> 5, d4 = e & 31;
            ((float4*)KV)[e] =
                ((const float4*)(kv + ((size_t)(b * KVLEN + j0 + r)) * 2048 + h * DH_))[d4];
        }
#pragma unroll
        for (int c = 0; c < 8; ++c) {
            int e = tid + 256 * c;               // up to 2048
            int r = e >> 5, d4 = e & 31;
            if (r < 63) {
                int p = pb + r;
                float4 v = make_float4(0.f, 0.f, 0.f, 0.f);
                if (p < KVLEN)
                    v = ((const float4*)(pe + ((size_t)(h * KVLEN) + p) * DH_))[d4];
                ((float4*)PE)[e] = v;
            }
        }
        __syncthreads();
        // ---- scores: partial dots over owned d-slice, all 32 keys ----
        float part[32];
#pragma unroll
        for (int kk = 0; kk < 32; ++kk) {
            const float4* kp = (const float4*)KV[kk];
            const float4* pp = (const float4*)PE[kk + 31 - qi];
            float s = 0.f;
#pragma unroll
            for (int c = 0; c < 4; ++c) {
                float4 k4 = kp[g + 8 * c];
                float4 p4 = pp[g + 8 * c];
                float4 q4 = qr[c];
                s = fmaf(q4.x, k4.x + p4.x, s);
                s = fmaf(q4.y, k4.y + p4.y, s);
                s = fmaf(q4.z, k4.z + p4.z, s);
                s = fmaf(q4.w, k4.w + p4.w, s);
            }
            part[kk] = s;
        }
        // 8-lane all-reduce (lanes of one query row)
#pragma unroll
        for (int st = 1; st < 8; st <<= 1)
#pragma unroll
            for (int kk = 0; kk < 32; ++kk)
                part[kk] += __shfl_xor(part[kk], st, 8);
        // ---- mask + online softmax ----
        float tmax = -INFINITY;
#pragma unroll
        for (int kk = 0; kk < 32; ++kk) {
            if (j0 + kk > i + 1280) part[kk] = -INFINITY;
            tmax = fmaxf(tmax, part[kk]);
        }
        float mnew = fmaxf(mrow, tmax);
        float fact = __expf(mrow - mnew);        // first tile: exp(-inf)=0
        float psum = 0.f;
#pragma unroll
        for (int kk = 0; kk < 32; ++kk) {
            part[kk] = __expf(part[kk] - mnew);  // masked -> 0
            psum += part[kk];
        }
        lrow = lrow * fact + psum;
        mrow = mnew;
        if (g == 0) {
            RS[qi] = fact;
#pragma unroll
            for (int c = 0; c < 8; ++c)
                *(float4*)&S[qi][c * 4] = make_float4(part[4*c], part[4*c+1],
                                                      part[4*c+2], part[4*c+3]);
        }
        __syncthreads();
        // ---- stage V into KV buffer ----
#pragma unroll
        for (int c = 0; c < 4; ++c) {
            int e = tid + 256 * c;
            int r = e >> 5, d4 = e & 31;
            ((float4*)KV)[e] =
                ((const float4*)(kv + ((size_t)(b * KVLEN + j0 + r)) * 2048 + 1024 + h * DH_))[d4];
        }
        __syncthreads();
        // ---- PV (d-parallel mapping) ----
        float f2 = RS[qv];
#pragma unroll
        for (int c = 0; c < 16; ++c) o[c] *= f2;
#pragma unroll
        for (int kk = 0; kk < 32; ++kk) {
            float p = S[qv][kk];
            const float4* vp = (const float4*)KV[kk];
#pragma unroll
            for (int c = 0; c < 4; ++c) {
                float4 v4 = vp[d4base + c];
                o[4*c+0] = fmaf(p, v4.x, o[4*c+0]);
                o[4*c+1] = fmaf(p, v4.y, o[4*c+1]);
                o[4*c+2] = fmaf(p, v4.z, o[4*c+2]);
                o[4*c+3] = fmaf(p, v4.w, o[4*c+3]);
            }
        }
    }
    // ---- epilogue ----
    if (g == 0) LN[qi] = lrow;
    __syncthreads();
    float inv = 1.0f / LN[qv];
    float* op = outb + ((size_t)(b * T_ + i0 + qv)) * E_ + h * DH_;
#pragma unroll
    for (int c = 0; c < 4; ++c) {
        float4 v = make_float4(o[4*c+0] * inv, o[4*c+1] * inv,
                               o[4*c+2] * inv, o[4*c+3] * inv);
        ((float4*)op)[d4base + c] = v;
    }
}

// ---------------------------------------------------------------------------
// Aux loss (unchanged this round)
// ---------------------------------------------------------------------------
__global__ __launch_bounds__(256)
void attn_aux_kernel(const float* __restrict__ q, const float* __restrict__ kv,
                     const float* __restrict__ ckv, float* __restrict__ accum)
{
    __shared__ float qs[DH_];
    __shared__ float sc[MEM_];
    __shared__ float red[256];
    __shared__ float o1[DH_];
    const int bid = blockIdx.x;
    const int i = bid & (T_ - 1), h = (bid >> 10) & 7, b = bid >> 13;
    const int tid = threadIdx.x;

    if (tid < DH_) qs[tid] = q[((size_t)(b * T_ + i)) * E_ + h * DH_ + tid] * SCALE;
    __syncthreads();
    const float4* q4 = (const float4*)qs;

    for (int j = tid; j < MEM_; j += 256) {
        const float4* kp = (const float4*)(kv + ((size_t)(b * KVLEN + CMEM_ + j)) * 2048 + h * DH_);
        float dot = 0.f;
#pragma unroll 8
        for (int d4 = 0; d4 < 32; ++d4) {
            float4 qv = q4[d4], kk = kp[d4];
            dot = fmaf(qv.x, kk.x, fmaf(qv.y, kk.y, fmaf(qv.z, kk.z, fmaf(qv.w, kk.w, dot))));
        }
        sc[j] = dot;
    }
    __syncthreads();
    float m = fmaxf(fmaxf(sc[tid], sc[tid + 256]), fmaxf(sc[tid + 512], sc[tid + 768]));
    red[tid] = m; __syncthreads();
    for (int s = 128; s > 0; s >>= 1) { if (tid < s) red[tid] = fmaxf(red[tid], red[tid + s]); __syncthreads(); }
    m = red[0]; __syncthreads();
    float lsum = 0.f;
    for (int j = tid; j < MEM_; j += 256) { float e = __expf(sc[j] - m); sc[j] = e; lsum += e; }
    red[tid] = lsum; __syncthreads();
    for (int s = 128; s > 0; s >>= 1) { if (tid < s) red[tid] += red[tid + s]; __syncthreads(); }
    const float inv1 = 1.f / red[0]; __syncthreads();

    const int d = tid & 127, hs = tid >> 7;
    float acc = 0.f;
    const float* vb = kv + 1024 + h * DH_ + d;
    for (int j = hs * 512; j < hs * 512 + 512; ++j)
        acc = fmaf(sc[j], vb[((size_t)(b * KVLEN + CMEM_ + j)) * 2048], acc);
    red[tid] = acc; __syncthreads();
    if (tid < 128) o1[tid] = (red[tid] + red[tid + 128]) * inv1;
    __syncthreads();

    {
        const float4* kp = (const float4*)(ckv + ((size_t)(b * CMEM_ + tid)) * 2048 + h * DH_);
        float dot = 0.f;
#pragma unroll 8
        for (int d4 = 0; d4 < 32; ++d4) {
            float4 qv = q4[d4], kk = kp[d4];
            dot = fmaf(qv.x, kk.x, fmaf(qv.y, kk.y, fmaf(qv.z, kk.z, fmaf(qv.w, kk.w, dot))));
        }
        sc[tid] = dot;
    }
    __syncthreads();
    red[tid] = sc[tid]; __syncthreads();
    for (int s = 128; s > 0; s >>= 1) { if (tid < s) red[tid] = fmaxf(red[tid], red[tid + s]); __syncthreads(); }
    m = red[0]; __syncthreads();
    float e2 = __expf(sc[tid] - m); sc[tid] = e2;
    red[tid] = e2; __syncthreads();
    for (int s = 128; s > 0; s >>= 1) { if (tid < s) red[tid] += red[tid + s]; __syncthreads(); }
    const float inv2 = 1.f / red[0]; __syncthreads();

    acc = 0.f;
    const float* vb2 = ckv + 1024 + h * DH_ + d;
    for (int j = hs * 128; j < hs * 128 + 128; ++j)
        acc = fmaf(sc[j], vb2[((size_t)(b * CMEM_ + j)) * 2048], acc);
    red[tid] = acc; __syncthreads();
    float sse = 0.f;
    if (tid < 128) { float diff = (red[tid] + red[tid + 128]) * inv2 - o1[tid]; sse = diff * diff; }
    __syncthreads();
    red[tid] = sse; __syncthreads();
    for (int s = 128; s > 0; s >>= 1) { if (tid < s) red[tid] += red[tid + s]; __syncthreads(); }
    if (tid == 0) atomicAdd(accum, red[0]);
}

__global__ void zero_kernel(float* p) { if (threadIdx.x == 0) p[0] = 0.f; }

__global__ void finalize_kernel(const float* __restrict__ accum, float* __restrict__ out)
{
    out[0] = accum[0] * (1.0f / 4194304.0f);
}

__global__ __launch_bounds__(256)
void copy_f32_kernel(const float* __restrict__ in, float* __restrict__ out, int n4)
{
    int idx = blockIdx.x * 256 + threadIdx.x;
    int stride = gridDim.x * 256;
    const float4* in4 = (const float4*)in;
    float4* out4 = (float4*)out;
    for (int i = idx; i < n4; i += stride) out4[i] = in4[i];
}

// ---------------------------------------------------------------------------
extern "C" void kernel_launch(void* const* d_in, const int* in_sizes, int n_in,
                              void* d_out, int out_size, void* d_ws, size_t ws_size,
                              hipStream_t stream)
{
    const float* x      = (const float*)d_in[0];
    const float* mem    = (const float*)d_in[1];
    const float* cmem   = (const float*)d_in[2];
    const float* pos    = (const float*)d_in[3];
    const float* w_q    = (const float*)d_in[4];
    const float* w_kv   = (const float*)d_in[5];
    const float* w_out  = (const float*)d_in[6];
    const float* b_out  = (const float*)d_in[7];
    const float* conv_w = (const float*)d_in[8];
    const float* conv_b = (const float*)d_in[9];
    float* out = (float*)d_out;          // f32: logits | new_mem | new_cmem | aux

    float* ws     = (float*)d_ws;
    float* q      = ws;                  // 4,194,304
    float* kv     = q     + 4194304;     // 18,874,368 (k | v per row of 2048)
    float* attno  = kv    + 18874368;    // 4,194,304
    float* comp   = attno + 4194304;     // 1,048,576
    float* ckv    = comp  + 1048576;     // 2,097,152
    float* accum  = ckv   + 2097152;     // 1

    dim3 blk(256);

    gemm_kernel<0><<<dim3(1024/64, 4096/64), blk, 0, stream>>>(
        x, w_q, nullptr, q, 4096, 1024, 1024, nullptr, nullptr, nullptr);
    gemm_kernel<1><<<dim3(2048/64, 9216/64), blk, 0, stream>>>(
        nullptr, w_kv, nullptr, kv, 9216, 2048, 1024, cmem, mem, x);
    gemm_kernel<2><<<dim3(1024/64, 1024/64), blk, 0, stream>>>(
        nullptr, conv_w, conv_b, comp, 1024, 1024, 4096, mem, nullptr, nullptr);
    gemm_kernel<0><<<dim3(2048/64, 1024/64), blk, 0, stream>>>(
        comp, w_kv, nullptr, ckv, 1024, 2048, 1024, nullptr, nullptr, nullptr);
    // tiled fused attention: grid = B*H*(T/32) = 1024 blocks
    attn_tiled_kernel<<<dim3(B_*H_*(T_/32)), blk, 0, stream>>>(q, kv, pos, attno);
    gemm_kernel<0><<<dim3(1024/64, 4096/64), blk, 0, stream>>>(
        attno, w_out, b_out, out, 4096, 1024, 1024, nullptr, nullptr, nullptr);
    copy_f32_kernel<<<dim3(2048), blk, 0, stream>>>(x, out + 4194304, 4194304 / 4);
    copy_f32_kernel<<<dim3(1024), blk, 0, stream>>>(comp, out + 8388608, 1048576 / 4);
    zero_kernel<<<1, 64, 0, stream>>>(accum);
    attn_aux_kernel<<<dim3(B_*H_*T_), blk, 0, stream>>>(q, kv, ckv, accum);
    finalize_kernel<<<1, 1, 0, stream>>>(accum, out + 9437184);
}

// Round 10
// 2998.043 us; speedup vs baseline: 4.4202x; 2.5066x over previous
//
#include <hip/hip_runtime.h>
#include <hip/hip_bf16.h>
#include <math.h>

// Problem constants
#define B_    4
#define T_    1024
#define E_    1024
#define H_    8
#define DH_   128
#define MEM_  1024
#define CMEM_ 256
#define KVLEN 2304              // CMEM + MEM + T
#define SCALE 0.08838834764831845f   // 1/sqrt(128)

typedef __attribute__((ext_vector_type(8))) short short8t;   // 8 bf16 (4 VGPR)
typedef __attribute__((ext_vector_type(4))) float f32x4;     // MFMA acc

static inline __device__ ushort f2bf(float f)
{
    __hip_bfloat16 h = __float2bfloat16(f);
    return *reinterpret_cast<ushort*>(&h);
}

// ---------------------------------------------------------------------------
// MFMA bf16 GEMM: C[M,N] = A[M,K] @ B[N,K]^T (+bias), f32 in/out, bf16 compute.
// 64x64 tile, 4 waves, each wave owns a 32x32 quadrant = 2x2 16x16x32 MFMAs.
// A/B staged to LDS with on-the-fly f32->bf16 (no extra workspace).
// AMODE 0: plain A. 1: A rows gather concat(cmem,mem,x). 2: im2col of mem.
// Fragment layout (m89-verified): A/B lane: row/col = l&15, k = (l>>4)*8+j;
// C/D: col = l&15, row = (l>>4)*4 + reg.
// ---------------------------------------------------------------------------
template<int AMODE>
__global__ __launch_bounds__(256)
void gemm_mfma_kernel(const float* __restrict__ A, const float* __restrict__ Bm,
                      const float* __restrict__ bias, float* __restrict__ C,
                      int M, int N, int K,
                      const float* __restrict__ aux0, const float* __restrict__ aux1,
                      const float* __restrict__ aux2)
{
    __shared__ ushort As[64][40];   // +8 pad: 80B row stride, 16B-aligned
    __shared__ ushort Bs[64][40];
    const int bm = blockIdx.y * 64, bn = blockIdx.x * 64;
    const int tid = threadIdx.x;
    const int wv = tid >> 6, ln = tid & 63;
    const int wr = (wv >> 1) * 32, wc = (wv & 1) * 32;  // wave quadrant origin
    const int fr = ln & 15, fk = ln >> 4;               // frag row/col, k-group
    const int sm = tid >> 2;                            // staging row 0..63
    const int sk = (tid & 3) * 8;                       // staging k 0,8,16,24

    f32x4 acc00 = {0.f,0.f,0.f,0.f}, acc01 = {0.f,0.f,0.f,0.f};
    f32x4 acc10 = {0.f,0.f,0.f,0.f}, acc11 = {0.f,0.f,0.f,0.f};

    for (int k0 = 0; k0 < K; k0 += 32) {
        // ---- stage A (64 x 32 bf16) ----
        {
            float va[8];
            if (AMODE == 0) {
                const float4* p = (const float4*)(A + (size_t)(bm + sm) * K + k0 + sk);
                float4 x0 = p[0], x1 = p[1];
                va[0]=x0.x; va[1]=x0.y; va[2]=x0.z; va[3]=x0.w;
                va[4]=x1.x; va[5]=x1.y; va[6]=x1.z; va[7]=x1.w;
            } else if (AMODE == 1) {
                int row = bm + sm; int b = row / KVLEN, t = row % KVLEN;
                const float* src;
                if (t < CMEM_)             src = aux0 + ((size_t)(b * CMEM_ + t)) * E_;
                else if (t < CMEM_ + MEM_) src = aux1 + ((size_t)(b * MEM_ + (t - CMEM_))) * E_;
                else                       src = aux2 + ((size_t)(b * T_ + (t - CMEM_ - MEM_))) * E_;
                const float4* p = (const float4*)(src + k0 + sk);
                float4 x0 = p[0], x1 = p[1];
                va[0]=x0.x; va[1]=x0.y; va[2]=x0.z; va[3]=x0.w;
                va[4]=x1.x; va[5]=x1.y; va[6]=x1.z; va[7]=x1.w;
            } else {
                int row = bm + sm; int b = row >> 8, s = row & 255;
#pragma unroll
                for (int j = 0; j < 8; ++j) {
                    int k = k0 + sk + j;
                    va[j] = aux0[((size_t)(b * MEM_) + 4 * s + (k & 3)) * E_ + (k >> 2)];
                }
            }
            short8t u;
#pragma unroll
            for (int j = 0; j < 8; ++j) u[j] = (short)f2bf(va[j]);
            *(short8t*)&As[sm][sk] = u;
        }
        // ---- stage B (64 x 32 bf16) ----
        {
            const float4* p = (const float4*)(Bm + (size_t)(bn + sm) * K + k0 + sk);
            float4 x0 = p[0], x1 = p[1];
            short8t u;
            u[0]=(short)f2bf(x0.x); u[1]=(short)f2bf(x0.y);
            u[2]=(short)f2bf(x0.z); u[3]=(short)f2bf(x0.w);
            u[4]=(short)f2bf(x1.x); u[5]=(short)f2bf(x1.y);
            u[6]=(short)f2bf(x1.z); u[7]=(short)f2bf(x1.w);
            *(short8t*)&Bs[sm][sk] = u;
        }
        __syncthreads();
        short8t a0 = *(short8t*)&As[wr + fr     ][fk * 8];
        short8t a1 = *(short8t*)&As[wr + 16 + fr][fk * 8];
        short8t b0 = *(short8t*)&Bs[wc + fr     ][fk * 8];
        short8t b1 = *(short8t*)&Bs[wc + 16 + fr][fk * 8];
        acc00 = __builtin_amdgcn_mfma_f32_16x16x32_bf16(a0, b0, acc00, 0, 0, 0);
        acc01 = __builtin_amdgcn_mfma_f32_16x16x32_bf16(a0, b1, acc01, 0, 0, 0);
        acc10 = __builtin_amdgcn_mfma_f32_16x16x32_bf16(a1, b0, acc10, 0, 0, 0);
        acc11 = __builtin_amdgcn_mfma_f32_16x16x32_bf16(a1, b1, acc11, 0, 0, 0);
        __syncthreads();
    }
    // ---- C write: row = (l>>4)*4+reg (M), col = l&15 (N) ----
#pragma unroll
    for (int reg = 0; reg < 4; ++reg) {
        int r0 = bm + wr + fk * 4 + reg;
        int c0 = bn + wc + fr;
        float v00 = acc00[reg], v01 = acc01[reg], v10 = acc10[reg], v11 = acc11[reg];
        if (bias) {
            v00 += bias[c0];      v01 += bias[c0 + 16];
            v10 += bias[c0];      v11 += bias[c0 + 16];
        }
        C[(size_t)r0 * N + c0]           = v00;
        C[(size_t)r0 * N + c0 + 16]      = v01;
        C[(size_t)(r0 + 16) * N + c0]    = v10;
        C[(size_t)(r0 + 16) * N + c0 + 16] = v11;
    }
}

// ---------------------------------------------------------------------------
// Tiled main attention (unchanged from round 9 — validated).
// ---------------------------------------------------------------------------
__global__ __launch_bounds__(256)
void attn_tiled_kernel(const float* __restrict__ q, const float* __restrict__ kv,
                       const float* __restrict__ pe, float* __restrict__ outb)
{
    __shared__ float KV[32][128];
    __shared__ float PE[64][128];
    __shared__ float S[32][36];
    __shared__ float RS[32];
    __shared__ float LN[32];

    const int bid = blockIdx.x;
    const int it = bid & 31, h = (bid >> 5) & 7, b = bid >> 8;
    const int i0 = it * 32;
    const int tid = threadIdx.x;
    const int qi = tid >> 3, g = tid & 7;
    const int i  = i0 + qi;
    const int w = tid >> 6, l = tid & 63;
    const int qv = l >> 1;
    const int d4base = w * 8 + (l & 1) * 4;

    float4 qr[4];
    {
        const float4* qp = (const float4*)(q + ((size_t)(b * T_ + i)) * E_ + h * DH_);
#pragma unroll
        for (int c = 0; c < 4; ++c) {
            float4 v = qp[g + 8 * c];
            v.x *= SCALE; v.y *= SCALE; v.z *= SCALE; v.w *= SCALE;
            qr[c] = v;
        }
    }
    float o[16];
#pragma unroll
    for (int c = 0; c < 16; ++c) o[c] = 0.f;
    float mrow = -INFINITY, lrow = 0.f;

    const int NT = it + 41;
    for (int kt = 0; kt < NT; ++kt) {
        const int j0 = kt * 32;
        const int pb = j0 - i0 + 992;
        __syncthreads();
#pragma unroll
        for (int c = 0; c < 4; ++c) {
            int e = tid + 256 * c;
            int r = e >> 5, d4 = e & 31;
            ((float4*)KV)[e] =
                ((const float4*)(kv + ((size_t)(b * KVLEN + j0 + r)) * 2048 + h * DH_))[d4];
        }
#pragma unroll
        for (int c = 0; c < 8; ++c) {
            int e = tid + 256 * c;
            int r = e >> 5, d4 = e & 31;
            if (r < 63) {
                int p = pb + r;
                float4 v = make_float4(0.f, 0.f, 0.f, 0.f);
                if (p < KVLEN)
                    v = ((const float4*)(pe + ((size_t)(h * KVLEN) + p) * DH_))[d4];
                ((float4*)PE)[e] = v;
            }
        }
        __syncthreads();
        float part[32];
#pragma unroll
        for (int kk = 0; kk < 32; ++kk) {
            const float4* kp = (const float4*)KV[kk];
            const float4* pp = (const float4*)PE[kk + 31 - qi];
            float s = 0.f;
#pragma unroll
            for (int c = 0; c < 4; ++c) {
                float4 k4 = kp[g + 8 * c];
                float4 p4 = pp[g + 8 * c];
                float4 q4 = qr[c];
                s = fmaf(q4.x, k4.x + p4.x, s);
                s = fmaf(q4.y, k4.y + p4.y, s);
                s = fmaf(q4.z, k4.z + p4.z, s);
                s = fmaf(q4.w, k4.w + p4.w, s);
            }
            part[kk] = s;
        }
#pragma unroll
        for (int st = 1; st < 8; st <<= 1)
#pragma unroll
            for (int kk = 0; kk < 32; ++kk)
                part[kk] += __shfl_xor(part[kk], st, 8);
        float tmax = -INFINITY;
#pragma unroll
        for (int kk = 0; kk < 32; ++kk) {
            if (j0 + kk > i + 1280) part[kk] = -INFINITY;
            tmax = fmaxf(tmax, part[kk]);
        }
        float mnew = fmaxf(mrow, tmax);
        float fact = __expf(mrow - mnew);
        float psum = 0.f;
#pragma unroll
        for (int kk = 0; kk < 32; ++kk) {
            part[kk] = __expf(part[kk] - mnew);
            psum += part[kk];
        }
        lrow = lrow * fact + psum;
        mrow = mnew;
        if (g == 0) {
            RS[qi] = fact;
#pragma unroll
            for (int c = 0; c < 8; ++c)
                *(float4*)&S[qi][c * 4] = make_float4(part[4*c], part[4*c+1],
                                                      part[4*c+2], part[4*c+3]);
        }
        __syncthreads();
#pragma unroll
        for (int c = 0; c < 4; ++c) {
            int e = tid + 256 * c;
            int r = e >> 5, d4 = e & 31;
            ((float4*)KV)[e] =
                ((const float4*)(kv + ((size_t)(b * KVLEN + j0 + r)) * 2048 + 1024 + h * DH_))[d4];
        }
        __syncthreads();
        float f2 = RS[qv];
#pragma unroll
        for (int c = 0; c < 16; ++c) o[c] *= f2;
#pragma unroll
        for (int kk = 0; kk < 32; ++kk) {
            float p = S[qv][kk];
            const float4* vp = (const float4*)KV[kk];
#pragma unroll
            for (int c = 0; c < 4; ++c) {
                float4 v4 = vp[d4base + c];
                o[4*c+0] = fmaf(p, v4.x, o[4*c+0]);
                o[4*c+1] = fmaf(p, v4.y, o[4*c+1]);
                o[4*c+2] = fmaf(p, v4.z, o[4*c+2]);
                o[4*c+3] = fmaf(p, v4.w, o[4*c+3]);
            }
        }
    }
    if (g == 0) LN[qi] = lrow;
    __syncthreads();
    float inv = 1.0f / LN[qv];
    float* op = outb + ((size_t)(b * T_ + i0 + qv)) * E_ + h * DH_;
#pragma unroll
    for (int c = 0; c < 4; ++c) {
        float4 v = make_float4(o[4*c+0] * inv, o[4*c+1] * inv,
                               o[4*c+2] * inv, o[4*c+3] * inv);
        ((float4*)op)[d4base + c] = v;
    }
}

// ---------------------------------------------------------------------------
// Tiled aux loss: one block = 32 queries of one (b,h); 1024 blocks.
// Phase A: a1 = softmax(q.k[256:1280])@v over 32 key-tiles (no mask, no pe).
// Phase B: a2 over 8 ckv tiles. SSE = sum((a1-a2)^2) -> block reduce -> atomic.
// Same thread mappings as attn_tiled (validated).
// ---------------------------------------------------------------------------
__global__ __launch_bounds__(256)
void attn_aux_tiled_kernel(const float* __restrict__ q, const float* __restrict__ kv,
                           const float* __restrict__ ckv, float* __restrict__ accum)
{
    __shared__ float KV[32][128];
    __shared__ float S[32][36];
    __shared__ float RS[32];
    __shared__ float LN1[32], LN2[32];
    __shared__ float red[256];

    const int bid = blockIdx.x;
    const int it = bid & 31, h = (bid >> 5) & 7, b = bid >> 8;
    const int i0 = it * 32;
    const int tid = threadIdx.x;
    const int qi = tid >> 3, g = tid & 7;
    const int i  = i0 + qi;
    const int w = tid >> 6, l = tid & 63;
    const int qv = l >> 1;
    const int d4base = w * 8 + (l & 1) * 4;

    float4 qr[4];
    {
        const float4* qp = (const float4*)(q + ((size_t)(b * T_ + i)) * E_ + h * DH_);
#pragma unroll
        for (int c = 0; c < 4; ++c) {
            float4 v = qp[g + 8 * c];
            v.x *= SCALE; v.y *= SCALE; v.z *= SCALE; v.w *= SCALE;
            qr[c] = v;
        }
    }
    float o1[16], o2[16];
#pragma unroll
    for (int c = 0; c < 16; ++c) { o1[c] = 0.f; o2[c] = 0.f; }

    // ================= phase A: 32 tiles over kv rows [CMEM_, CMEM_+1024) ====
    float mrow = -INFINITY, lrow = 0.f;
    for (int kt = 0; kt < 32; ++kt) {
        const int j0 = kt * 32;
        __syncthreads();
#pragma unroll
        for (int c = 0; c < 4; ++c) {
            int e = tid + 256 * c;
            int r = e >> 5, d4 = e & 31;
            ((float4*)KV)[e] =
                ((const float4*)(kv + ((size_t)(b * KVLEN + CMEM_ + j0 + r)) * 2048 + h * DH_))[d4];
        }
        __syncthreads();
        float part[32];
#pragma unroll
        for (int kk = 0; kk < 32; ++kk) {
            const float4* kp = (const float4*)KV[kk];
            float s = 0.f;
#pragma unroll
            for (int c = 0; c < 4; ++c) {
                float4 k4 = kp[g + 8 * c];
                float4 q4 = qr[c];
                s = fmaf(q4.x, k4.x, s); s = fmaf(q4.y, k4.y, s);
                s = fmaf(q4.z, k4.z, s); s = fmaf(q4.w, k4.w, s);
            }
            part[kk] = s;
        }
#pragma unroll
        for (int st = 1; st < 8; st <<= 1)
#pragma unroll
            for (int kk = 0; kk < 32; ++kk)
                part[kk] += __shfl_xor(part[kk], st, 8);
        float tmax = -INFINITY;
#pragma unroll
        for (int kk = 0; kk < 32; ++kk) tmax = fmaxf(tmax, part[kk]);
        float mnew = fmaxf(mrow, tmax);
        float fact = __expf(mrow - mnew);
        float psum = 0.f;
#pragma unroll
        for (int kk = 0; kk < 32; ++kk) { part[kk] = __expf(part[kk] - mnew); psum += part[kk]; }
        lrow = lrow * fact + psum;
        mrow = mnew;
        if (g == 0) {
            RS[qi] = fact;
#pragma unroll
            for (int c = 0; c < 8; ++c)
                *(float4*)&S[qi][c * 4] = make_float4(part[4*c], part[4*c+1],
                                                      part[4*c+2], part[4*c+3]);
        }
        __syncthreads();
#pragma unroll
        for (int c = 0; c < 4; ++c) {
            int e = tid + 256 * c;
            int r = e >> 5, d4 = e & 31;
            ((float4*)KV)[e] =
                ((const float4*)(kv + ((size_t)(b * KVLEN + CMEM_ + j0 + r)) * 2048 + 1024 + h * DH_))[d4];
        }
        __syncthreads();
        float f2 = RS[qv];
#pragma unroll
        for (int c = 0; c < 16; ++c) o1[c] *= f2;
#pragma unroll
        for (int kk = 0; kk < 32; ++kk) {
            float p = S[qv][kk];
            const float4* vp = (const float4*)KV[kk];
#pragma unroll
            for (int c = 0; c < 4; ++c) {
                float4 v4 = vp[d4base + c];
                o1[4*c+0] = fmaf(p, v4.x, o1[4*c+0]);
                o1[4*c+1] = fmaf(p, v4.y, o1[4*c+1]);
                o1[4*c+2] = fmaf(p, v4.z, o1[4*c+2]);
                o1[4*c+3] = fmaf(p, v4.w, o1[4*c+3]);
            }
        }
    }
    if (g == 0) LN1[qi] = lrow;

    // ================= phase B: 8 tiles over ckv rows [0, 256) ===============
    mrow = -INFINITY; lrow = 0.f;
    for (int kt = 0; kt < 8; ++kt) {
        const int j0 = kt * 32;
        __syncthreads();
#pragma unroll
        for (int c = 0; c < 4; ++c) {
            int e = tid + 256 * c;
            int r = e >> 5, d4 = e & 31;
            ((float4*)KV)[e] =
                ((const float4*)(ckv + ((size_t)(b * CMEM_ + j0 + r)) * 2048 + h * DH_))[d4];
        }
        __syncthreads();
        float part[32];
#pragma unroll
        for (int kk = 0; kk < 32; ++kk) {
            const float4* kp = (const float4*)KV[kk];
            float s = 0.f;
#pragma unroll
            for (int c = 0; c < 4; ++c) {
                float4 k4 = kp[g + 8 * c];
                float4 q4 = qr[c];
                s = fmaf(q4.x, k4.x, s); s = fmaf(q4.y, k4.y, s);
                s = fmaf(q4.z, k4.z, s); s = fmaf(q4.w, k4.w, s);
            }
            part[kk] = s;
        }
#pragma unroll
        for (int st = 1; st < 8; st <<= 1)
#pragma unroll
            for (int kk = 0; kk < 32; ++kk)
                part[kk] += __shfl_xor(part[kk], st, 8);
        float tmax = -INFINITY;
#pragma unroll
        for (int kk = 0; kk < 32; ++kk) tmax = fmaxf(tmax, part[kk]);
        float mnew = fmaxf(mrow, tmax);
        float fact = __expf(mrow - mnew);
        float psum = 0.f;
#pragma unroll
        for (int kk = 0; kk < 32; ++kk) { part[kk] = __expf(part[kk] - mnew); psum += part[kk]; }
        lrow = lrow * fact + psum;
        mrow = mnew;
        if (g == 0) {
            RS[qi] = fact;
#pragma unroll
            for (int c = 0; c < 8; ++c)
                *(float4*)&S[qi][c * 4] = make_float4(part[4*c], part[4*c+1],
                                                      part[4*c+2], part[4*c+3]);
        }
        __syncthreads();
#pragma unroll
        for (int c = 0; c < 4; ++c) {
            int e = tid + 256 * c;
            int r = e >> 5, d4 = e & 31;
            ((float4*)KV)[e] =
                ((const float4*)(ckv + ((size_t)(b * CMEM_ + j0 + r)) * 2048 + 1024 + h * DH_))[d4];
        }
        __syncthreads();
        float f2 = RS[qv];
#pragma unroll
        for (int c = 0; c < 16; ++c) o2[c] *= f2;
#pragma unroll
        for (int kk = 0; kk < 32; ++kk) {
            float p = S[qv][kk];
            const float4* vp = (const float4*)KV[kk];
#pragma unroll
            for (int c = 0; c < 4; ++c) {
                float4 v4 = vp[d4base + c];
                o2[4*c+0] = fmaf(p, v4.x, o2[4*c+0]);
                o2[4*c+1] = fmaf(p, v4.y, o2[4*c+1]);
                o2[4*c+2] = fmaf(p, v4.z, o2[4*c+2]);
                o2[4*c+3] = fmaf(p, v4.w, o2[4*c+3]);
            }
        }
    }
    if (g == 0) LN2[qi] = lrow;
    __syncthreads();

    // ================= SSE reduce ===========================================
    float inv1 = 1.0f / LN1[qv], inv2 = 1.0f / LN2[qv];
    float sse = 0.f;
#pragma unroll
    for (int c = 0; c < 16; ++c) {
        float d = o1[c] * inv1 - o2[c] * inv2;
        sse = fmaf(d, d, sse);
    }
    red[tid] = sse; __syncthreads();
    for (int s = 128; s > 0; s >>= 1) {
        if (tid < s) red[tid] += red[tid + s];
        __syncthreads();
    }
    if (tid == 0) atomicAdd(accum, red[0]);
}

__global__ void zero_kernel(float* p) { if (threadIdx.x == 0) p[0] = 0.f; }

__global__ void finalize_kernel(const float* __restrict__ accum, float* __restrict__ out)
{
    out[0] = accum[0] * (1.0f / 4194304.0f);
}

__global__ __launch_bounds__(256)
void copy_f32_kernel(const float* __restrict__ in, float* __restrict__ out, int n4)
{
    int idx = blockIdx.x * 256 + threadIdx.x;
    int stride = gridDim.x * 256;
    const float4* in4 = (const float4*)in;
    float4* out4 = (float4*)out;
    for (int i = idx; i < n4; i += stride) out4[i] = in4[i];
}

// ---------------------------------------------------------------------------
extern "C" void kernel_launch(void* const* d_in, const int* in_sizes, int n_in,
                              void* d_out, int out_size, void* d_ws, size_t ws_size,
                              hipStream_t stream)
{
    const float* x      = (const float*)d_in[0];
    const float* mem    = (const float*)d_in[1];
    const float* cmem   = (const float*)d_in[2];
    const float* pos    = (const float*)d_in[3];
    const float* w_q    = (const float*)d_in[4];
    const float* w_kv   = (const float*)d_in[5];
    const float* w_out  = (const float*)d_in[6];
    const float* b_out  = (const float*)d_in[7];
    const float* conv_w = (const float*)d_in[8];
    const float* conv_b = (const float*)d_in[9];
    float* out = (float*)d_out;          // f32: logits | new_mem | new_cmem | aux

    float* ws     = (float*)d_ws;
    float* q      = ws;                  // 4,194,304
    float* kv     = q     + 4194304;     // 18,874,368 (k | v per row of 2048)
    float* attno  = kv    + 18874368;    // 4,194,304
    float* comp   = attno + 4194304;     // 1,048,576
    float* ckv    = comp  + 1048576;     // 2,097,152
    float* accum  = ckv   + 2097152;     // 1

    dim3 blk(256);

    // q = x @ w_q^T                               (4096 x 1024 x 1024)
    gemm_mfma_kernel<0><<<dim3(1024/64, 4096/64), blk, 0, stream>>>(
        x, w_q, nullptr, q, 4096, 1024, 1024, nullptr, nullptr, nullptr);
    // kv = concat(cmem,mem,x) @ w_kv^T            (9216 x 2048 x 1024)
    gemm_mfma_kernel<1><<<dim3(2048/64, 9216/64), blk, 0, stream>>>(
        nullptr, w_kv, nullptr, kv, 9216, 2048, 1024, cmem, mem, x);
    // compressed = conv(mem) as GEMM              (1024 x 1024 x 4096)
    gemm_mfma_kernel<2><<<dim3(1024/64, 1024/64), blk, 0, stream>>>(
        nullptr, conv_w, conv_b, comp, 1024, 1024, 4096, mem, nullptr, nullptr);
    // ckv = compressed @ w_kv^T                   (1024 x 2048 x 1024)
    gemm_mfma_kernel<0><<<dim3(2048/64, 1024/64), blk, 0, stream>>>(
        comp, w_kv, nullptr, ckv, 1024, 2048, 1024, nullptr, nullptr, nullptr);
    // tiled fused attention: grid = B*H*(T/32) = 1024 blocks
    attn_tiled_kernel<<<dim3(B_*H_*(T_/32)), blk, 0, stream>>>(q, kv, pos, attno);
    // logits = attn_out @ w_out^T + b_out  -> f32 d_out[0 : 4194304)
    gemm_mfma_kernel<0><<<dim3(1024/64, 4096/64), blk, 0, stream>>>(
        attno, w_out, b_out, out, 4096, 1024, 1024, nullptr, nullptr, nullptr);
    // new_mem = x                          -> f32 d_out[4194304 : 8388608)
    copy_f32_kernel<<<dim3(2048), blk, 0, stream>>>(x, out + 4194304, 4194304 / 4);
    // new_cmem = compressed                -> f32 d_out[8388608 : 9437184)
    copy_f32_kernel<<<dim3(1024), blk, 0, stream>>>(comp, out + 8388608, 1048576 / 4);
    // aux loss                             -> f32 d_out[9437184]
    zero_kernel<<<1, 64, 0, stream>>>(accum);
    attn_aux_tiled_kernel<<<dim3(B_*H_*(T_/32)), blk, 0, stream>>>(q, kv, ckv, accum);
    finalize_kernel<<<1, 1, 0, stream>>>(accum, out + 9437184);
}